// Round 1
// baseline (2927.532 us; speedup 1.0000x reference)
//
#include <hip/hip_runtime.h>
#include <stdint.h>

typedef unsigned int u32;

#define NB   2048
#define SS   256
#define HH   64
#define VV   4
#define LATD 3
#define NTHR 512   // 8 waves; wave pair (2p,2p+1) = rows (2p,2p+1), K split across the pair

// float-element offsets in d_out: recons [B,S,1,V], tokens [B,S], mu, log_var
#define TOK_OFF (NB*SS*VV)
#define MU_OFF  (TOK_OFF + NB*SS)
#define LV_OFF  (MU_OFF + NB*LATD)

// ---------- JAX threefry2x32 (20 rounds, explicit) ----------
__device__ __forceinline__ void tf2x32(u32 k0, u32 k1, u32 x0, u32 x1, u32& o0, u32& o1){
  u32 k2 = k0 ^ k1 ^ 0x1BD11BDAu;
  x0 += k0; x1 += k1;
#define TFR(r) { x0 += x1; x1 = (x1<<r)|(x1>>(32-r)); x1 ^= x0; }
  TFR(13) TFR(15) TFR(26) TFR(6)   x0 += k1; x1 += k2 + 1u;
  TFR(17) TFR(29) TFR(16) TFR(24)  x0 += k2; x1 += k0 + 2u;
  TFR(13) TFR(15) TFR(26) TFR(6)   x0 += k0; x1 += k1 + 3u;
  TFR(17) TFR(29) TFR(16) TFR(24)  x0 += k1; x1 += k2 + 4u;
  TFR(13) TFR(15) TFR(26) TFR(6)   x0 += k2; x1 += k0 + 5u;
#undef TFR
  o0 = x0; o1 = x1;
}
__device__ __forceinline__ u32 foldb(u32 k0, u32 k1, u32 i){
  u32 a,b; tf2x32(k0,k1,0u,i,a,b); return a^b;
}
__device__ __forceinline__ float b2u(u32 bits){
  union{u32 i;float f;}c; c.i = (bits>>9) | 0x3f800000u; return c.f - 1.0f;
}
// XLA ErfInv32 (Giles)
__device__ __forceinline__ float erfinv_f(float x){
  float w = -log1pf(-x*x);
  float p;
  if (w < 5.0f){
    w -= 2.5f;
    p = 2.81022636e-08f;
    p = fmaf(p,w, 3.43273939e-07f);
    p = fmaf(p,w,-3.5233877e-06f);
    p = fmaf(p,w,-4.39150654e-06f);
    p = fmaf(p,w, 0.00021858087f);
    p = fmaf(p,w,-0.00125372503f);
    p = fmaf(p,w,-0.00417768164f);
    p = fmaf(p,w, 0.246640727f);
    p = fmaf(p,w, 1.50140941f);
  } else {
    w = sqrtf(w) - 3.0f;
    p = -0.000200214257f;
    p = fmaf(p,w, 0.000100950558f);
    p = fmaf(p,w, 0.00134934322f);
    p = fmaf(p,w,-0.00367342844f);
    p = fmaf(p,w, 0.00573950773f);
    p = fmaf(p,w,-0.0076224613f);
    p = fmaf(p,w, 0.00943887047f);
    p = fmaf(p,w, 1.00167406f);
    p = fmaf(p,w, 2.83297682f);
  }
  return p*x;
}
__device__ __forceinline__ float sigm(float x){ return 1.0f/(1.0f+expf(-x)); }
__device__ __forceinline__ float rl(float x, int l){
  return __int_as_float(__builtin_amdgcn_readlane(__float_as_int(x), l));
}
__device__ __forceinline__ float wred(float x){
  #pragma unroll
  for (int m=1; m<64; m<<=1) x += __shfl_xor(x, m, 64);
  return x;
}

#define PIN4(v) asm volatile("" : "+v"(v.x), "+v"(v.y), "+v"(v.z), "+v"(v.w))
#define PIN_W8(Ar, Az, An)                                                     \
  _Pragma("unroll")                                                            \
  for (int k4 = 0; k4 < 8; k4++){ PIN4(Ar[k4]); PIN4(An[k4]); PIN4(Az[k4]); }

// Layer-0 mat-vec: REGISTER weights (half-K per wave), two rows (A,B).
// w0r/w0z/w0n hold this wave's K-half; broadcasts start at lane kb0 = kh*32.
#define MATVEC0P(hA, hB)                                                       \
  _Pragma("unroll")                                                            \
  for (int k4 = 0; k4 < 8; k4++){                                              \
    float4 wr = w0r[k4], wz = w0z[k4], wn = w0n[k4];                           \
    int kb = kb0 + 4*k4;                                                       \
    float a0=rl(hA,kb), a1=rl(hA,kb+1), a2=rl(hA,kb+2), a3=rl(hA,kb+3);        \
    float c0=rl(hB,kb), c1=rl(hB,kb+1), c2=rl(hB,kb+2), c3=rl(hB,kb+3);        \
    arA=fmaf(wr.x,a0,arA); arA=fmaf(wr.y,a1,arA); arA=fmaf(wr.z,a2,arA); arA=fmaf(wr.w,a3,arA); \
    azA=fmaf(wz.x,a0,azA); azA=fmaf(wz.y,a1,azA); azA=fmaf(wz.z,a2,azA); azA=fmaf(wz.w,a3,azA); \
    anA=fmaf(wn.x,a0,anA); anA=fmaf(wn.y,a1,anA); anA=fmaf(wn.z,a2,anA); anA=fmaf(wn.w,a3,anA); \
    arB=fmaf(wr.x,c0,arB); arB=fmaf(wr.y,c1,arB); arB=fmaf(wr.z,c2,arB); arB=fmaf(wr.w,c3,arB); \
    azB=fmaf(wz.x,c0,azB); azB=fmaf(wz.y,c1,azB); azB=fmaf(wz.z,c2,azB); azB=fmaf(wz.w,c3,azB); \
    anB=fmaf(wn.x,c0,anB); anB=fmaf(wn.y,c1,anB); anB=fmaf(wn.z,c2,anB); anB=fmaf(wn.w,c3,anB); \
  }

// Layer-1 mat-vec: LDS weights (half-K per wave), each weight float4 read ONCE
// and used for BOTH rows (this is the 2x LDS-traffic reduction).
// r,z accumulate ih+hh combined; n keeps ih (in*) and hh (hn*) separate.
#define MATVEC1P(xA, xB, yA, yB)                                               \
  _Pragma("unroll 2")                                                          \
  for (int k4 = 0; k4 < 8; k4++){                                              \
    int ki = kh8 + k4;                                                         \
    float4 wir = wi1[ki*192 + j],  wiz = wi1[ki*192 + 64 + j],  win = wi1[ki*192 + 128 + j]; \
    float4 whr = wh1[ki*192 + j],  whz = wh1[ki*192 + 64 + j],  whn = wh1[ki*192 + 128 + j]; \
    int kb = 4*ki;                                                             \
    float xa0=rl(xA,kb), xa1=rl(xA,kb+1), xa2=rl(xA,kb+2), xa3=rl(xA,kb+3);    \
    float xb0=rl(xB,kb), xb1=rl(xB,kb+1), xb2=rl(xB,kb+2), xb3=rl(xB,kb+3);    \
    float ya0=rl(yA,kb), ya1=rl(yA,kb+1), ya2=rl(yA,kb+2), ya3=rl(yA,kb+3);    \
    float yb0=rl(yB,kb), yb1=rl(yB,kb+1), yb2=rl(yB,kb+2), yb3=rl(yB,kb+3);    \
    srA=fmaf(wir.x,xa0,srA); srA=fmaf(wir.y,xa1,srA); srA=fmaf(wir.z,xa2,srA); srA=fmaf(wir.w,xa3,srA); \
    srA=fmaf(whr.x,ya0,srA); srA=fmaf(whr.y,ya1,srA); srA=fmaf(whr.z,ya2,srA); srA=fmaf(whr.w,ya3,srA); \
    szA=fmaf(wiz.x,xa0,szA); szA=fmaf(wiz.y,xa1,szA); szA=fmaf(wiz.z,xa2,szA); szA=fmaf(wiz.w,xa3,szA); \
    szA=fmaf(whz.x,ya0,szA); szA=fmaf(whz.y,ya1,szA); szA=fmaf(whz.z,ya2,szA); szA=fmaf(whz.w,ya3,szA); \
    inA=fmaf(win.x,xa0,inA); inA=fmaf(win.y,xa1,inA); inA=fmaf(win.z,xa2,inA); inA=fmaf(win.w,xa3,inA); \
    hnA=fmaf(whn.x,ya0,hnA); hnA=fmaf(whn.y,ya1,hnA); hnA=fmaf(whn.z,ya2,hnA); hnA=fmaf(whn.w,ya3,hnA); \
    srB=fmaf(wir.x,xb0,srB); srB=fmaf(wir.y,xb1,srB); srB=fmaf(wir.z,xb2,srB); srB=fmaf(wir.w,xb3,srB); \
    srB=fmaf(whr.x,yb0,srB); srB=fmaf(whr.y,yb1,srB); srB=fmaf(whr.z,yb2,srB); srB=fmaf(whr.w,yb3,srB); \
    szB=fmaf(wiz.x,xb0,szB); szB=fmaf(wiz.y,xb1,szB); szB=fmaf(wiz.z,xb2,szB); szB=fmaf(wiz.w,xb3,szB); \
    szB=fmaf(whz.x,yb0,szB); szB=fmaf(whz.y,yb1,szB); szB=fmaf(whz.z,yb2,szB); szB=fmaf(whz.w,yb3,szB); \
    inB=fmaf(win.x,xb0,inB); inB=fmaf(win.y,xb1,inB); inB=fmaf(win.z,xb2,inB); inB=fmaf(win.w,xb3,inB); \
    hnB=fmaf(whn.x,yb0,hnB); hnB=fmaf(whn.y,yb1,hnB); hnB=fmaf(whn.z,yb2,hnB); hnB=fmaf(whn.w,yb3,hnB); \
  }

// =====================================================================
// Encoder: pair-K-split. Wave pair (2p,2p+1) jointly owns rows (2p,2p+1);
// each wave does half the K range for BOTH rows. Layer-0 weights (96 f32)
// now fit in registers (no scratch stream); layer-1 LDS traffic halved.
// Partial sums exchanged via small LDS buffers, 2 barriers/timestep.
// Single-buffered exchange is safe: each write(t+1) is separated from the
// partner's read(t) of the same buffer by a __syncthreads().
// =====================================================================
__global__ __launch_bounds__(NTHR, 2) void enc_kernel(
    const int* __restrict__ tokens, const float* __restrict__ emb,
    const float* __restrict__ Wih0, const float* __restrict__ Whh0,
    const float* __restrict__ bih0, const float* __restrict__ bhh0,
    const float* __restrict__ Wih1, const float* __restrict__ Whh1,
    const float* __restrict__ bih1, const float* __restrict__ bhh1,
    const float* __restrict__ muW, const float* __restrict__ mub,
    const float* __restrict__ vaW, const float* __restrict__ vab,
    const float* __restrict__ pW,  const float* __restrict__ pb,
    float* __restrict__ out, float* __restrict__ hz_ws)
{
  __shared__ float4 wi1[16*192];   // enc_Wih1
  __shared__ float4 wh1[16*192];   // enc_Whh1
  __shared__ float tokT[VV*192];   // input-gate table (incl. bih0) per vocab token
  __shared__ float4 ex1a[8][64];   // layer-0 partials {arA,azA,anA,arB}
  __shared__ float2 ex1b[8][64];   // layer-0 partials {azB,anB}
  __shared__ float4 ex2a[8][64];   // layer-1 partials row A {srA,szA,inA,hnA}
  __shared__ float4 ex2b[8][64];   // layer-1 partials row B

  const int tid = threadIdx.x;
  const int b0  = blockIdx.x * 8;
  const int j   = tid & 63;
  const int wv  = tid >> 6;
  const int kh  = wv & 1;          // K-half of this wave
  const int pw  = wv ^ 1;          // partner wave
  const int rA  = b0 + (wv & ~1);  // pair's first row
  const int rB  = rA + 1;
  const int rD  = b0 + wv;         // designated row for tail (== old mapping)
  const int kh8 = kh * 8;
  const int kb0 = kh * 32;

  for (int i4 = tid; i4 < 3072; i4 += NTHR){
    int g = i4 >> 4, k4 = i4 & 15;
    wi1[k4*192 + g] = ((const float4*)Wih1)[i4];
    wh1[k4*192 + g] = ((const float4*)Whh1)[i4];
  }
  if (tid < 192){
    #pragma unroll
    for (int v = 0; v < VV; v++){
      float acc = 0.0f;
      #pragma unroll
      for (int e = 0; e < 8; e++) acc = fmaf(emb[v*8+e], Wih0[tid*8+e], acc);
      tokT[v*192 + tid] = acc + bih0[tid];
    }
  }
  for (int i = tid; i < 8*SS; i += NTHR){
    int rr = i >> 8, tq = i & 255;
    out[TOK_OFF + (b0+rr)*SS + tq] = (float)tokens[(b0+rr)*SS + tq];
  }

  // layer-0 recurrent weights: this wave's K-half only (3*8 float4 = 96 VGPRs)
  float4 w0r[8], w0z[8], w0n[8];
  {
    const float4* G0 = (const float4*)Whh0;
    #pragma unroll
    for (int k4 = 0; k4 < 8; k4++){
      w0r[k4] = G0[(j)*16      + kh8 + k4];
      w0z[k4] = G0[(64 + j)*16 + kh8 + k4];
      w0n[k4] = G0[(128 + j)*16+ kh8 + k4];
    }
    PIN_W8(w0r, w0z, w0n)
  }
  __syncthreads();

  const float bhr0 = bhh0[j], bhz0 = bhh0[64+j], bhn0 = bhh0[128+j];
  const float bR1  = bih1[j]      + bhh1[j];
  const float bZ1  = bih1[64+j]   + bhh1[64+j];
  const float bin1 = bih1[128+j], bhn1 = bhh1[128+j];

  float h0A = 0.0f, h0B = 0.0f, h1A = 0.0f, h1B = 0.0f;

  for (int t = 0; t < SS; t++){
    asm volatile("" ::: "memory");   // LICM fence (hoist -> spill protection)
    int kA = tokens[rA*SS + t];
    int kB = tokens[rB*SS + t];
    // ---- layer 0: half-K partials for both rows ----
    float arA=0, azA=0, anA=0, arB=0, azB=0, anB=0;
    MATVEC0P(h0A, h0B)
    ex1a[wv][j] = make_float4(arA, azA, anA, arB);
    ex1b[wv][j] = make_float2(azB, anB);
    __syncthreads();                  // barrier 1
    {
      float4 qa = ex1a[pw][j]; float2 qb = ex1b[pw][j];
      arA += qa.x; azA += qa.y; anA += qa.z;
      arB += qa.w; azB += qb.x; anB += qb.y;
    }
    {
      float ir = tokT[kA*192+j], iz = tokT[kA*192+64+j], ig = tokT[kA*192+128+j];
      float rg = sigm(ir + arA + bhr0);
      float zg = sigm(iz + azA + bhz0);
      float ng = tanhf(ig + rg*(anA + bhn0));
      h0A = (1.0f - zg)*ng + zg*h0A;
    }
    {
      float ir = tokT[kB*192+j], iz = tokT[kB*192+64+j], ig = tokT[kB*192+128+j];
      float rg = sigm(ir + arB + bhr0);
      float zg = sigm(iz + azB + bhz0);
      float ng = tanhf(ig + rg*(anB + bhn0));
      h0B = (1.0f - zg)*ng + zg*h0B;
    }
    // ---- layer 1: half-K, shared weight reads for both rows ----
    float srA=0, szA=0, inA=0, hnA=0, srB=0, szB=0, inB=0, hnB=0;
    MATVEC1P(h0A, h0B, h1A, h1B)
    ex2a[wv][j] = make_float4(srA, szA, inA, hnA);
    ex2b[wv][j] = make_float4(srB, szB, inB, hnB);
    __syncthreads();                  // barrier 2
    {
      float4 pa = ex2a[pw][j];
      float rg = sigm(srA + pa.x + bR1);
      float zg = sigm(szA + pa.y + bZ1);
      float ng = tanhf(inA + pa.z + bin1 + rg*(hnA + pa.w + bhn1));
      h1A = (1.0f - zg)*ng + zg*h1A;
      float4 pb = ex2b[pw][j];
      rg = sigm(srB + pb.x + bR1);
      zg = sigm(szB + pb.y + bZ1);
      ng = tanhf(inB + pb.z + bin1 + rg*(hnB + pb.w + bhn1));
      h1B = (1.0f - zg)*ng + zg*h1B;
    }
  }

  // ---- tail: each wave handles its designated row rD = b0 + wv ----
  const float LO_ = -0.99999994f;   // nextafter(-1, 0) in f32
  {
    float hv = kh ? h1B : h1A;
    int gb = rD;
    float mu0,mu1,mu2, lv0,lv1,lv2;
    { float pm = muW[0*64+j]*hv; pm = wred(pm); mu0 = pm + mub[0];
      float pv = vaW[0*64+j]*hv; pv = wred(pv); lv0 = pv + vab[0]; }
    { float pm = muW[1*64+j]*hv; pm = wred(pm); mu1 = pm + mub[1];
      float pv = vaW[1*64+j]*hv; pv = wred(pv); lv1 = pv + vab[1]; }
    { float pm = muW[2*64+j]*hv; pm = wred(pm); mu2 = pm + mub[2];
      float pv = vaW[2*64+j]*hv; pv = wred(pv); lv2 = pv + vab[2]; }
    if (j < 3){
      float mv  = (j==0)?mu0:(j==1)?mu1:mu2;
      float lvv = (j==0)?lv0:(j==1)?lv1:lv2;
      out[MU_OFF + gb*LATD + j] = mv;
      out[LV_OFF + gb*LATD + j] = lvv;
    }
    float z0,z1,z2;
    #pragma unroll
    for (int l = 0; l < 3; l++){
      u32 bits = foldb(0u, 1u, (u32)(gb*LATD + l));
      float u01 = b2u(bits);
      float uu = u01 * 2.0f;
      uu = uu + LO_;
      uu = fmaxf(LO_, uu);
      float ep = 1.41421354f * erfinv_f(uu);
      float lvv = (l==0)?lv0:(l==1)?lv1:lv2;
      float mvv = (l==0)?mu0:(l==1)?mu1:mu2;
      float zv = ep * expf(0.5f*lvv) + mvv;
      if (l==0) z0 = zv; else if (l==1) z1 = zv; else z2 = zv;
    }
    float hzj = pW[j*3+0]*z0;
    hzj += pW[j*3+1]*z1;
    hzj += pW[j*3+2]*z2;
    hzj += pb[j];
    hz_ws[gb*HH + j] = hzj;
  }
}

// =====================================================================
// Decoder: same pair-K-split structure. Head/sample per designated row;
// sampled token published through a single-buffered LDS slot (read after
// barrier 1 of the next timestep — fenced by barrier 2 in between).
// =====================================================================
__global__ __launch_bounds__(NTHR, 2) void dec_kernel(
    const float* __restrict__ demb,
    const float* __restrict__ Wih0, const float* __restrict__ Whh0,
    const float* __restrict__ bih0, const float* __restrict__ bhh0,
    const float* __restrict__ Wih1, const float* __restrict__ Whh1,
    const float* __restrict__ bih1, const float* __restrict__ bhh1,
    const float* __restrict__ headW, const float* __restrict__ headb,
    const float* __restrict__ hz_ws, float* __restrict__ out)
{
  __shared__ float4 wi1[16*192];   // dec_Wih1
  __shared__ float4 wh1[16*192];   // dec_Whh1
  __shared__ float decT[6*192];    // input-gate table (incl. bih0) per token
  __shared__ u32 sk0[SS], sk1[SS];
  __shared__ int tokS[8];          // sampled token per row of this block
  __shared__ float4 ex1a[8][64];
  __shared__ float2 ex1b[8][64];
  __shared__ float4 ex2a[8][64];
  __shared__ float4 ex2b[8][64];

  const int tid = threadIdx.x;
  const int b0  = blockIdx.x * 8;
  const int j   = tid & 63;
  const int wv  = tid >> 6;
  const int kh  = wv & 1;
  const int pw  = wv ^ 1;
  const int rA  = b0 + (wv & ~1);
  const int rB  = rA + 1;
  const int rD  = b0 + wv;
  const int kh8 = kh * 8;
  const int kb0 = kh * 32;
  const int pbase = wv & ~1;

  for (int i4 = tid; i4 < 3072; i4 += NTHR){
    int g = i4 >> 4, k4 = i4 & 15;
    wi1[k4*192 + g] = ((const float4*)Wih1)[i4];
    wh1[k4*192 + g] = ((const float4*)Whh1)[i4];
  }
  if (tid < 192){
    #pragma unroll
    for (int v = 0; v < 6; v++){
      float acc = 0.0f;
      #pragma unroll 8
      for (int k = 0; k < 64; k++) acc = fmaf(demb[v*64+k], Wih0[tid*64+k], acc);
      decT[v*192 + tid] = acc + bih0[tid];
    }
  }
  if (tid < SS){
    u32 a,b; tf2x32(0u, 2u, 0u, (u32)tid, a, b);
    sk0[tid] = a; sk1[tid] = b;
  }
  if (tid < 8) tokS[tid] = 4;      // START token

  float4 w0r[8], w0z[8], w0n[8];
  {
    const float4* G0 = (const float4*)Whh0;
    #pragma unroll
    for (int k4 = 0; k4 < 8; k4++){
      w0r[k4] = G0[(j)*16      + kh8 + k4];
      w0z[k4] = G0[(64 + j)*16 + kh8 + k4];
      w0n[k4] = G0[(128 + j)*16+ kh8 + k4];
    }
    PIN_W8(w0r, w0z, w0n)
  }
  __syncthreads();

  const float bhr0 = bhh0[j], bhz0 = bhh0[64+j], bhn0 = bhh0[128+j];
  const float bR1  = bih1[j]      + bhh1[j];
  const float bZ1  = bih1[64+j]   + bhh1[64+j];
  const float bin1 = bih1[128+j], bhn1 = bhh1[128+j];
  const float hw0 = headW[0*64+j], hw1 = headW[1*64+j], hw2 = headW[2*64+j], hw3 = headW[3*64+j];
  const float hb0 = headb[0], hb1 = headb[1], hb2 = headb[2], hb3 = headb[3];

  float h0A = hz_ws[rA*HH + j];
  float h0B = hz_ws[rB*HH + j];
  float h1A = h0A, h1B = h0B;

  const int vv = j & 3;
  const float TINY = 1.17549435e-38f;

  for (int t = 0; t < SS; t++){
    asm volatile("" ::: "memory");   // LICM fence
    // ---- layer 0: half-K partials for both rows ----
    float arA=0, azA=0, anA=0, arB=0, azB=0, anB=0;
    MATVEC0P(h0A, h0B)
    ex1a[wv][j] = make_float4(arA, azA, anA, arB);
    ex1b[wv][j] = make_float2(azB, anB);
    __syncthreads();                  // barrier 1
    int tkA = tokS[pbase];
    int tkB = tokS[pbase+1];
    {
      float4 qa = ex1a[pw][j]; float2 qb = ex1b[pw][j];
      arA += qa.x; azA += qa.y; anA += qa.z;
      arB += qa.w; azB += qb.x; anB += qb.y;
    }
    {
      float ir = decT[tkA*192+j], iz = decT[tkA*192+64+j], ig = decT[tkA*192+128+j];
      float rg = sigm(ir + arA + bhr0);
      float zg = sigm(iz + azA + bhz0);
      float ng = tanhf(ig + rg*(anA + bhn0));
      h0A = (1.0f - zg)*ng + zg*h0A;
    }
    {
      float ir = decT[tkB*192+j], iz = decT[tkB*192+64+j], ig = decT[tkB*192+128+j];
      float rg = sigm(ir + arB + bhr0);
      float zg = sigm(iz + azB + bhz0);
      float ng = tanhf(ig + rg*(anB + bhn0));
      h0B = (1.0f - zg)*ng + zg*h0B;
    }
    // ---- layer 1: half-K, shared weight reads ----
    float srA=0, szA=0, inA=0, hnA=0, srB=0, szB=0, inB=0, hnB=0;
    MATVEC1P(h0A, h0B, h1A, h1B)
    ex2a[wv][j] = make_float4(srA, szA, inA, hnA);
    ex2b[wv][j] = make_float4(srB, szB, inB, hnB);
    __syncthreads();                  // barrier 2
    {
      float4 pa = ex2a[pw][j];
      float rg = sigm(srA + pa.x + bR1);
      float zg = sigm(szA + pa.y + bZ1);
      float ng = tanhf(inA + pa.z + bin1 + rg*(hnA + pa.w + bhn1));
      h1A = (1.0f - zg)*ng + zg*h1A;
      float4 pb = ex2b[pw][j];
      rg = sigm(srB + pb.x + bR1);
      zg = sigm(szB + pb.y + bZ1);
      ng = tanhf(inB + pb.z + bin1 + rg*(hnB + pb.w + bhn1));
      h1B = (1.0f - zg)*ng + zg*h1B;
    }
    // ---- head + gumbel sample for designated row rD ----
    float hD = kh ? h1B : h1A;
    float l0 = wred(hw0*hD) + hb0;
    float l1 = wred(hw1*hD) + hb1;
    float l2 = wred(hw2*hD) + hb2;
    float l3 = wred(hw3*hD) + hb3;
    float lg = (vv==0)?l0:(vv==1)?l1:(vv==2)?l2:l3;
    u32 bits = foldb(sk0[t], sk1[t], (u32)(rD*VV + vv));
    float u01 = b2u(bits);
    float u = u01 + TINY;
    u = fmaxf(TINY, u);
    float gmb = -logf(-logf(u));
    float prt = lg + gmb;
    float mx = lg;
    mx = fmaxf(mx, __shfl_xor(mx, 1, 64));
    mx = fmaxf(mx, __shfl_xor(mx, 2, 64));
    float e = expf(lg - mx);
    float se = e;
    se += __shfl_xor(se, 1, 64);
    se += __shfl_xor(se, 2, 64);
    float prob = e / se;
    float bp = prt; int bv = vv;
    { float o = __shfl_xor(bp, 1, 64); int ov = __shfl_xor(bv, 1, 64);
      if (o > bp || (o == bp && ov < bv)){ bp = o; bv = ov; } }
    { float o = __shfl_xor(bp, 2, 64); int ov = __shfl_xor(bv, 2, 64);
      if (o > bp || (o == bp && ov < bv)){ bp = o; bv = ov; } }
    if (j < 4) out[(size_t)rD*SS*VV + (size_t)t*VV + vv] = prob;
    int tkD = __builtin_amdgcn_readlane(bv, 0);
    if (j == 0) tokS[wv] = tkD;   // published for next timestep (read after barrier 1)
  }
}

extern "C" void kernel_launch(void* const* d_in, const int* in_sizes, int n_in,
                              void* d_out, int out_size, void* d_ws, size_t ws_size,
                              hipStream_t stream){
  const int*   tokens = (const int*)d_in[0];
  const float* emb    = (const float*)d_in[1];
  const float* eWih0  = (const float*)d_in[2];  const float* eWhh0 = (const float*)d_in[3];
  const float* ebih0  = (const float*)d_in[4];  const float* ebhh0 = (const float*)d_in[5];
  const float* eWih1  = (const float*)d_in[6];  const float* eWhh1 = (const float*)d_in[7];
  const float* ebih1  = (const float*)d_in[8];  const float* ebhh1 = (const float*)d_in[9];
  const float* muW    = (const float*)d_in[10]; const float* mub   = (const float*)d_in[11];
  const float* vaW    = (const float*)d_in[12]; const float* vab   = (const float*)d_in[13];
  const float* demb   = (const float*)d_in[14];
  const float* pW     = (const float*)d_in[15]; const float* pb    = (const float*)d_in[16];
  const float* dWih0  = (const float*)d_in[17]; const float* dWhh0 = (const float*)d_in[18];
  const float* dbih0  = (const float*)d_in[19]; const float* dbhh0 = (const float*)d_in[20];
  const float* dWih1  = (const float*)d_in[21]; const float* dWhh1 = (const float*)d_in[22];
  const float* dbih1  = (const float*)d_in[23]; const float* dbhh1 = (const float*)d_in[24];
  const float* hWp    = (const float*)d_in[25]; const float* hbp   = (const float*)d_in[26];
  float* out = (float*)d_out;
  float* hz = (float*)d_ws;   // B*H fp32 = 512 KB scratch

  enc_kernel<<<NB/8, NTHR, 0, stream>>>(tokens, emb,
      eWih0, eWhh0, ebih0, ebhh0, eWih1, eWhh1, ebih1, ebhh1,
      muW, mub, vaW, vab, pW, pb, out, hz);
  dec_kernel<<<NB/8, NTHR, 0, stream>>>(demb,
      dWih0, dWhh0, dbih0, dbhh0, dWih1, dWhh1, dbih1, dbhh1,
      hWp, hbp, hz, out);
}